// Round 6
// baseline (2951.398 us; speedup 1.0000x reference)
//
#include <hip/hip_runtime.h>

#define NROWS 8192
#define NG    12972
#define H     1000
#define NP    1024   // padded hidden width
#define KX    288    // padded hints width (multiple of 32)
#define OCP   256    // padded output cols
#define OC    130
#define EPSBN 1e-5f
#define MBLK  (NROWS / 128)   // 64 row-blocks => 64 stat partials

typedef __attribute__((ext_vector_type(8))) short bf16x8;
typedef __attribute__((ext_vector_type(4))) float f32x4;

__device__ __forceinline__ float lrelu(float x) { return x >= 0.f ? x : 0.2f * x; }
__device__ __forceinline__ unsigned short f2bf(float f) {
    unsigned u = __float_as_uint(f);
    return (unsigned short)((u + 0x7fffu + ((u >> 16) & 1u)) >> 16);
}
__device__ __forceinline__ float bf2f(unsigned short h) {
    return __uint_as_float(((unsigned)h) << 16);
}

// ---------------- prep: transpose + split fp32 -> bf16 hi/lo, B^T layout ----------------
__global__ void transpose_split(const float* __restrict__ src, int R, int C, int srcStride,
                                unsigned short* __restrict__ dhi, unsigned short* __restrict__ dlo,
                                int Rp, int Cp) {
    __shared__ float tile[32][33];
    int k0 = blockIdx.x * 32;
    int n0 = blockIdx.y * 32;
    int tx = threadIdx.x, ty = threadIdx.y;  // 32 x 8
#pragma unroll
    for (int i = 0; i < 32; i += 8) {
        int k = k0 + ty + i, n = n0 + tx;
        tile[ty + i][tx] = (k < R && n < C) ? src[(size_t)k * srcStride + n] : 0.f;
    }
    __syncthreads();
#pragma unroll
    for (int i = 0; i < 32; i += 8) {
        int n = n0 + ty + i, k = k0 + tx;
        if (n < Cp && k < Rp) {
            float v = tile[tx][ty + i];
            unsigned short hi = f2bf(v);
            dhi[(size_t)n * Rp + k] = hi;
            dlo[(size_t)n * Rp + k] = f2bf(v - bf2f(hi));
        }
    }
}

__global__ void prep_bias(const float* __restrict__ W0, const float* __restrict__ b0,
                          const float* __restrict__ bh, const float* __restrict__ bout,
                          float* __restrict__ b0p, float* __restrict__ w0t,
                          float* __restrict__ bhp, float* __restrict__ boutp) {
    int i = blockIdx.x * 256 + threadIdx.x;
    if (i < 1024) { b0p[i] = (i < H) ? b0[i] : 0.f; return; }
    i -= 1024;
    if (i < 6 * 1024) {
        int t = i >> 10, n = i & 1023;
        w0t[i] = (n < H) ? W0[(size_t)(286 + t) * H + n] : 0.f;
        return;
    }
    i -= 6 * 1024;
    if (i < 3 * 1024) {
        int l = i >> 10, n = i & 1023;
        bhp[i] = (n < H) ? bh[l * H + n] : 0.f;
        return;
    }
    i -= 3 * 1024;
    if (i < OCP) { boutp[i] = (i < OC) ? bout[i] : 0.f; }
}

// gl: letters (for hint update). glp: packed softmax offsets letter*5+p (5 bytes in uint2).
__global__ void prep_guess_letters(const float* __restrict__ gm, unsigned char* __restrict__ gl,
                                   uint2* __restrict__ glp) {
    int g = blockIdx.x * blockDim.x + threadIdx.x;
    if (g >= NG) return;
    unsigned off[5];
    for (int p = 0; p < 5; ++p) {
        int letter = 0;
        for (int c = 0; c < 26; ++c)
            if (gm[(size_t)g * 130 + c * 5 + p] > 0.5f) { letter = c; break; }
        gl[g * 8 + p] = (unsigned char)letter;
        off[p] = (unsigned)(letter * 5 + p);
    }
    gl[g * 8 + 5] = gl[g * 8 + 6] = gl[g * 8 + 7] = 0;
    glp[g] = make_uint2(off[0] | (off[1] << 8) | (off[2] << 16) | (off[3] << 24), off[4]);
}

__global__ void prep_sol_letters(const float* __restrict__ sols, unsigned char* __restrict__ sl,
                                 unsigned int* __restrict__ msk) {
    int r = blockIdx.x * blockDim.x + threadIdx.x;
    if (r >= NROWS) return;
    unsigned int m = 0;
    for (int p = 0; p < 5; ++p) {
        int letter = 0;
        for (int c = 0; c < 26; ++c)
            if (sols[(size_t)r * 130 + c * 5 + p] > 0.5f) { letter = c; break; }
        sl[r * 8 + p] = (unsigned char)letter;
        m |= 1u << letter;
    }
    sl[r * 8 + 5] = sl[r * 8 + 6] = sl[r * 8 + 7] = 0;
    msk[r] = m;
}

__global__ void init_state(unsigned short* __restrict__ hXh, float* __restrict__ scores,
                           int* __restrict__ solvedf, float* __restrict__ lossacc) {
    int i = blockIdx.x * blockDim.x + threadIdx.x;
    if (i < NROWS * KX) hXh[i] = 0;
    if (i < NROWS) { scores[i] = 7.f; solvedf[i] = 0; }
    if (i == 0) lossacc[0] = 0.f;
}

// ---------------- GEMM: C = Ah*Bh + Ah*Bl (+ Al*Bh) (+bias), fused column stats ----------------
// Tile 128x64 (M x N) -> grid 64 x (N/64): 1024 blocks for N=1024 => 4 blocks/CU, 16 waves/CU.
// 4 waves (2x2), wave tile 64x32, BK=32, single LDS buffer, round-3 two-barrier loop.
// HAS_AL=false: A exact in bf16 (Al==0), 2 MFMA passes.
template <bool HAS_AL>
__global__ __launch_bounds__(256, 4) void gemm_bf16x2(
    const unsigned short* __restrict__ Ah, const unsigned short* __restrict__ Al, int lda,
    const unsigned short* __restrict__ Bh, const unsigned short* __restrict__ Bl, int ldb,
    float* __restrict__ C, int ldc,
    const float* __restrict__ bias1, const float* __restrict__ bias2, int kiter,
    float* __restrict__ pS, float* __restrict__ pS2) {
    constexpr int NCH = HAS_AL ? 6 : 4;              // 256-thread x 16B staging chunks per K-tile
    constexpr int BUFSZ = HAS_AL ? 24576 : 16384;
    constexpr int offAl = 8192;                       // (HAS_AL only)
    constexpr int offBh = HAS_AL ? 16384 : 8192;
    constexpr int offBl = offBh + 4096;
    __shared__ char smem[BUFSZ];
    const int tid = threadIdx.x;
    const int lane = tid & 63;
    const int rowBase = blockIdx.x * 128;
    const int colBase = blockIdx.y * 64;
    const int wm = (tid >> 6) & 1;
    const int wn = tid >> 7;

    // staging map: 16B word w = i*256 + tid.
    //   HAS_AL : [Ah 512][Al 512][Bh 256][Bl 256]   (A word: r=w&127, kb=(w>>7)&3; B word: col=v&63, kb=v>>6)
    //   !HAS_AL: [Ah 512][Bh 256][Bl 256]
    const unsigned short* gsrc[NCH];
    int ldsuni[NCH];
#pragma unroll
    for (int i = 0; i < NCH; ++i) {
        int w = i * 256 + tid;
        const unsigned short* plane;
        int off;  // element offset within plane's panel
        constexpr int AW = HAS_AL ? 1024 : 512;  // A words
        if (w < AW) {
            plane = (HAS_AL && w >= 512) ? Al : Ah;
            int aw = w & 511;
            int r = aw & 127, kb = aw >> 7;
            off = (rowBase + r) * lda + kb * 8;
        } else {
            int v = w - AW;
            plane = (v >= 256) ? Bl : Bh;
            int idx = v & 255;
            int col = idx & 63, kb = idx >> 6;
            off = (colBase + col) * ldb + kb * 8;
        }
        gsrc[i] = plane + off;
        ldsuni[i] = (i * 256 + (tid & ~63)) * 16;  // wave-uniform byte base
    }

    f32x4 acc[4][2];
    const f32x4 z = {0.f, 0.f, 0.f, 0.f};
#pragma unroll
    for (int m = 0; m < 4; ++m)
#pragma unroll
        for (int n = 0; n < 2; ++n) acc[m][n] = z;

    const int aro = (lane >> 4) * 2048 + (wm * 64 + (lane & 15)) * 16;
    const int bco = (lane >> 4) * 1024 + (wn * 32 + (lane & 15)) * 16;

    for (int t = 0; t < kiter; ++t) {
#pragma unroll
        for (int i = 0; i < NCH; ++i)
            __builtin_amdgcn_global_load_lds(
                (const __attribute__((address_space(1))) void*)(gsrc[i] + (size_t)t * 32),
                (__attribute__((address_space(3))) void*)(smem + ldsuni[i]), 16, 0, 0);
        __syncthreads();

        bf16x8 a_h[4], a_l[4], b_h[2], b_l[2];
#pragma unroll
        for (int m = 0; m < 4; ++m) {
            a_h[m] = *(const bf16x8*)(smem + aro + m * 256);
            if constexpr (HAS_AL) a_l[m] = *(const bf16x8*)(smem + offAl + aro + m * 256);
        }
#pragma unroll
        for (int n = 0; n < 2; ++n) {
            b_h[n] = *(const bf16x8*)(smem + offBh + bco + n * 256);
            b_l[n] = *(const bf16x8*)(smem + offBl + bco + n * 256);
        }
#pragma unroll
        for (int m = 0; m < 4; ++m)
#pragma unroll
            for (int n = 0; n < 2; ++n) {
                acc[m][n] = __builtin_amdgcn_mfma_f32_16x16x32_bf16(a_h[m], b_h[n], acc[m][n], 0, 0, 0);
                acc[m][n] = __builtin_amdgcn_mfma_f32_16x16x32_bf16(a_h[m], b_l[n], acc[m][n], 0, 0, 0);
                if constexpr (HAS_AL)
                    acc[m][n] = __builtin_amdgcn_mfma_f32_16x16x32_bf16(a_l[m], b_h[n], acc[m][n], 0, 0, 0);
            }
        __syncthreads();
    }

    // epilogue (smem contents dead; last loop iter ended with __syncthreads)
    float* sS  = (float*)smem;           // [2][64]
    float* sS2 = (float*)smem + 128;     // [2][64]
    const int lane16 = lane & 15, lanehi = lane >> 4;
#pragma unroll
    for (int n = 0; n < 2; ++n) {
        int col = colBase + wn * 32 + n * 16 + lane16;
        float bv = bias1[col] + (bias2 ? bias2[col] : 0.f);
        float s = 0.f, s2 = 0.f;
#pragma unroll
        for (int m = 0; m < 4; ++m) {
            int row0 = rowBase + wm * 64 + m * 16 + lanehi * 4;
#pragma unroll
            for (int r = 0; r < 4; ++r) {
                float cv = acc[m][n][r] + bv;
                C[(size_t)(row0 + r) * ldc + col] = cv;
                s += cv; s2 += cv * cv;
            }
        }
        if (pS) {
            s += __shfl_xor(s, 16);  s += __shfl_xor(s, 32);
            s2 += __shfl_xor(s2, 16); s2 += __shfl_xor(s2, 32);
            if (lanehi == 0) {
                int lcol = wn * 32 + n * 16 + lane16;
                sS[wm * 64 + lcol] = s;
                sS2[wm * 64 + lcol] = s2;
            }
        }
    }
    if (pS) {
        __syncthreads();
        if (tid < 64) {
            int col = colBase + tid;
            pS[(size_t)blockIdx.x * NP + col] = sS[tid] + sS[64 + tid];
            pS2[(size_t)blockIdx.x * NP + col] = sS2[tid] + sS2[64 + tid];
        }
    }
}

// ---------------- fused BN finalize + apply + lrelu + bf16 hi/lo split ----------------
// grid (64 row-chunks, 8 col-chunks); each block reduces the 64 stat partials for its
// 128 columns (identical fp order to the old bn_final -> bit-exact), then applies to its
// 128x128 tile of hraw, writing hi/lo bf16 planes.
__global__ __launch_bounds__(256) void bn_apply_f(
    const float* __restrict__ hraw, const float* __restrict__ pS, const float* __restrict__ pS2,
    const float* __restrict__ gamma, const float* __restrict__ beta,
    unsigned short* __restrict__ oh, unsigned short* __restrict__ ol) {
    __shared__ float la[128], lb[128];
    const int tid = threadIdx.x;
    const int rowBase = blockIdx.x * 128;
    const int colBase = blockIdx.y * 128;
    if (tid < 128) {
        int col = colBase + tid;
        float s = 0.f;
        for (int j = 0; j < MBLK; ++j) s += pS[(size_t)j * NP + col];
        la[tid] = s;
    } else {
        int col = colBase + tid - 128;
        float s2 = 0.f;
        for (int j = 0; j < MBLK; ++j) s2 += pS2[(size_t)j * NP + col];
        lb[tid - 128] = s2;
    }
    __syncthreads();
    if (tid < 128) {
        int col = colBase + tid;
        float a = 0.f, b = 0.f;
        if (col < H) {
            float mean = la[tid] * (1.f / NROWS);
            float var = lb[tid] * (1.f / NROWS) - mean * mean;
            float inv = rsqrtf(var + EPSBN);
            a = gamma[col] * inv;
            b = beta[col] - mean * a;
        }
        la[tid] = a;
        lb[tid] = b;
    }
    __syncthreads();
#pragma unroll
    for (int i = 0; i < 16; ++i) {
        int idx = i * 256 + tid;            // 0..4095
        int row = idx >> 5;                 // 32 float4 per row
        int c4 = (idx & 31) * 4;
        const float4 v = *(const float4*)(hraw + (size_t)(rowBase + row) * NP + colBase + c4);
        float x0 = lrelu(la[c4] * v.x + lb[c4]);
        float x1 = lrelu(la[c4 + 1] * v.y + lb[c4 + 1]);
        float x2 = lrelu(la[c4 + 2] * v.z + lb[c4 + 2]);
        float x3 = lrelu(la[c4 + 3] * v.w + lb[c4 + 3]);
        unsigned short h0 = f2bf(x0), h1 = f2bf(x1), h2 = f2bf(x2), h3 = f2bf(x3);
        ushort4 hi = make_ushort4(h0, h1, h2, h3);
        ushort4 lo = make_ushort4(f2bf(x0 - bf2f(h0)), f2bf(x1 - bf2f(h1)),
                                  f2bf(x2 - bf2f(h2)), f2bf(x3 - bf2f(h3)));
        size_t o = (size_t)(rowBase + row) * NP + colBase + c4;
        *(ushort4*)(oh + o) = hi;
        *(ushort4*)(ol + o) = lo;
    }
}

// ---------------- fused per-turn tail: softmax + loss + vocab argmax + hints ----------------
__global__ __launch_bounds__(256) void post_turn(
    const float* __restrict__ ybuf, const uint2* __restrict__ glp,
    const unsigned char* __restrict__ gl, const unsigned char* __restrict__ sl,
    const unsigned int* __restrict__ msk, unsigned short* __restrict__ hXh,
    float* __restrict__ scores, int* __restrict__ solvedf, float* __restrict__ lossacc,
    const float* __restrict__ gm, float* __restrict__ dout, int turn) {
    const int r0 = blockIdx.x * 4;
    __shared__ float4 pk[130];           // pk[c] = {row0[c], row1[c], row2[c], row3[c]} softmax probs
    __shared__ float lcon[20];
    __shared__ float wb[4][4];
    __shared__ int wi[4][4];
    __shared__ int fidx[4];
    const int tid = threadIdx.x;

    if (tid < 20) {
        int row = tid / 5, p = tid - row * 5;
        const float* yr = ybuf + (size_t)(r0 + row) * OCP + p;
        float m = -1e30f;
#pragma unroll
        for (int c = 0; c < 26; ++c) m = fmaxf(m, yr[c * 5]);
        float e[26];
        float s = 0.f;
#pragma unroll
        for (int c = 0; c < 26; ++c) { e[c] = expf(yr[c * 5] - m); s += e[c]; }
        float inv = 1.f / s;
#pragma unroll
        for (int c = 0; c < 26; ++c) ((float*)&pk[c * 5 + p])[row] = e[c] * inv;
        lcon[tid] = logf(s) + m - yr[sl[(size_t)(r0 + row) * 8 + p] * 5];
    }
    __syncthreads();

    // vocab scan: 4 rows in parallel per thread
    float b0 = -1e30f, b1 = -1e30f, b2 = -1e30f, b3 = -1e30f;
    int i0 = 1 << 30, i1 = 1 << 30, i2 = 1 << 30, i3 = 1 << 30;
    for (int g = tid; g < NG; g += 256) {
        uint2 w = glp[g];
        float4 s0 = pk[w.x & 255];
        float4 s1 = pk[(w.x >> 8) & 255];
        float4 s2 = pk[(w.x >> 16) & 255];
        float4 s3 = pk[w.x >> 24];
        float4 s4 = pk[w.y & 255];
        // same left-assoc add order as reference gather
        float vx = s0.x + s1.x; vx += s2.x; vx += s3.x; vx += s4.x;
        float vy = s0.y + s1.y; vy += s2.y; vy += s3.y; vy += s4.y;
        float vz = s0.z + s1.z; vz += s2.z; vz += s3.z; vz += s4.z;
        float vw = s0.w + s1.w; vw += s2.w; vw += s3.w; vw += s4.w;
        if (vx > b0) { b0 = vx; i0 = g; }
        if (vy > b1) { b1 = vy; i1 = g; }
        if (vz > b2) { b2 = vz; i2 = g; }
        if (vw > b3) { b3 = vw; i3 = g; }
    }
#pragma unroll
    for (int off = 1; off < 64; off <<= 1) {
        float o; int oi;
        o = __shfl_xor(b0, off); oi = __shfl_xor(i0, off);
        if (o > b0 || (o == b0 && oi < i0)) { b0 = o; i0 = oi; }
        o = __shfl_xor(b1, off); oi = __shfl_xor(i1, off);
        if (o > b1 || (o == b1 && oi < i1)) { b1 = o; i1 = oi; }
        o = __shfl_xor(b2, off); oi = __shfl_xor(i2, off);
        if (o > b2 || (o == b2 && oi < i2)) { b2 = o; i2 = oi; }
        o = __shfl_xor(b3, off); oi = __shfl_xor(i3, off);
        if (o > b3 || (o == b3 && oi < i3)) { b3 = o; i3 = oi; }
    }
    const int wid = tid >> 6, lane = tid & 63;
    if (lane == 0) {
        wb[wid][0] = b0; wi[wid][0] = i0;
        wb[wid][1] = b1; wi[wid][1] = i1;
        wb[wid][2] = b2; wi[wid][2] = i2;
        wb[wid][3] = b3; wi[wid][3] = i3;
    }
    __syncthreads();

    if (tid < 4) {
        float b = wb[0][tid]; int x = wi[0][tid];
#pragma unroll
        for (int wv = 1; wv < 4; ++wv)
            if (wb[wv][tid] > b || (wb[wv][tid] == b && wi[wv][tid] < x)) { b = wb[wv][tid]; x = wi[wv][tid]; }
        fidx[tid] = x;
        // hints / scores / solved for row r0+tid
        int r = r0 + tid;
        const unsigned char* q = gl + x * 8;
        const unsigned char* so = sl + (size_t)r * 8;
        unsigned int mk = msk[r];
        unsigned short* hrow = hXh + (size_t)r * KX;
        int allg = 1;
#pragma unroll
        for (int p = 0; p < 5; ++p) {
            int g = q[p];
            int off;
            if (g == so[p]) {
                off = g * 5 + p;  // green
            } else {
                allg = 0;
                off = ((mk >> g) & 1u) ? (130 + g * 5 + p) : (260 + g);  // yellow : black
            }
            hrow[off] = f2bf(bf2f(hrow[off]) + 1.f);
        }
        solvedf[r] = allg;
        if (allg && scores[r] > (float)(turn + 1)) scores[r] = (float)(turn + 1);
    }
    if (tid == 8 && turn >= 1) {
        float t = 0.f;
#pragma unroll
        for (int j = 0; j < 20; ++j) t += lcon[j];
        atomicAdd(lossacc, t * (1.f / (NROWS * 5)));
    }
    __syncthreads();
    if (turn == 0 && blockIdx.x == 0 && tid >= 64 && tid < 64 + OC) {
        dout[3 + tid - 64] = gm[(size_t)fidx[0] * OC + (tid - 64)];
    }
}

__global__ void final_reduce(const float* __restrict__ scores, const int* __restrict__ solvedf,
                             const float* __restrict__ lossacc, float* __restrict__ dout) {
    __shared__ float rs[256];
    __shared__ int ri[256];
    int tid = threadIdx.x;
    float s = 0.f;
    int c = 0;
    for (int r = tid; r < NROWS; r += 256) { s += scores[r]; c += solvedf[r]; }
    rs[tid] = s; ri[tid] = c;
    __syncthreads();
    for (int off = 128; off > 0; off >>= 1) {
        if (tid < off) { rs[tid] += rs[tid + off]; ri[tid] += ri[tid + off]; }
        __syncthreads();
    }
    if (tid == 0) {
        dout[0] = lossacc[0];
        dout[1] = rs[0];
        dout[2] = (float)ri[0];
    }
}

// ---------------- launch ----------------
extern "C" void kernel_launch(void* const* d_in, const int* in_sizes, int n_in,
                              void* d_out, int out_size, void* d_ws, size_t ws_size,
                              hipStream_t stream) {
    const float* sols   = (const float*)d_in[0];
    const float* gm     = (const float*)d_in[1];
    const float* W0     = (const float*)d_in[2];
    const float* b0     = (const float*)d_in[3];
    const float* gammas = (const float*)d_in[4];
    const float* betas  = (const float*)d_in[5];
    const float* Wh     = (const float*)d_in[6];
    const float* bh     = (const float*)d_in[7];
    const float* Wout   = (const float*)d_in[8];
    const float* bout   = (const float*)d_in[9];
    float* dout = (float*)d_out;

    char* p = (char*)d_ws;
    auto alloc = [&](size_t bytes) { void* r = (void*)p; p += (bytes + 255) & ~(size_t)255; return r; };
    unsigned short* hXh = (unsigned short*)alloc((size_t)NROWS * KX * 2);
    unsigned short* hAh = (unsigned short*)alloc((size_t)NROWS * NP * 2);
    unsigned short* hAl = (unsigned short*)alloc((size_t)NROWS * NP * 2);
    float* hraw  = (float*)alloc((size_t)NROWS * NP * 4);
    float* ybuf  = hraw;   // alias: hraw dead when ybuf written (out layer)
    unsigned short* B0Th  = (unsigned short*)alloc((size_t)NP * KX * 2);
    unsigned short* B0Tl  = (unsigned short*)alloc((size_t)NP * KX * 2);
    unsigned short* WhTh  = (unsigned short*)alloc((size_t)3 * NP * NP * 2);
    unsigned short* WhTl  = (unsigned short*)alloc((size_t)3 * NP * NP * 2);
    unsigned short* BoTh  = (unsigned short*)alloc((size_t)OCP * NP * 2);
    unsigned short* BoTl  = (unsigned short*)alloc((size_t)OCP * NP * 2);
    float* b0p   = (float*)alloc(NP * 4);
    float* w0t   = (float*)alloc(6 * NP * 4);
    float* bhp   = (float*)alloc(3 * NP * 4);
    float* boutp = (float*)alloc(OCP * 4);
    float* pS    = (float*)alloc((size_t)MBLK * NP * 4);
    float* pS2   = (float*)alloc((size_t)MBLK * NP * 4);
    float* scores  = (float*)alloc(NROWS * 4);
    float* lossacc = (float*)alloc(256);
    int* solvedf = (int*)alloc(NROWS * 4);
    unsigned char* gl = (unsigned char*)alloc(NG * 8);
    uint2* glp = (uint2*)alloc(NG * 8);
    unsigned char* sl = (unsigned char*)alloc(NROWS * 8);
    unsigned int* msk = (unsigned int*)alloc(NROWS * 4);

    // ---- prep ----
    transpose_split<<<dim3(KX / 32, NP / 32), dim3(32, 8), 0, stream>>>(W0, 286, H, H, B0Th, B0Tl, KX, NP);
    for (int l = 0; l < 3; ++l)
        transpose_split<<<dim3(NP / 32, NP / 32), dim3(32, 8), 0, stream>>>(
            Wh + (size_t)l * H * H, H, H, H, WhTh + (size_t)l * NP * NP, WhTl + (size_t)l * NP * NP, NP, NP);
    transpose_split<<<dim3(NP / 32, OCP / 32), dim3(32, 8), 0, stream>>>(Wout, H, OC, OC, BoTh, BoTl, NP, OCP);
    prep_bias<<<41, 256, 0, stream>>>(W0, b0, bh, bout, b0p, w0t, bhp, boutp);
    prep_guess_letters<<<(NG + 255) / 256, 256, 0, stream>>>(gm, gl, glp);
    prep_sol_letters<<<(NROWS + 255) / 256, 256, 0, stream>>>(sols, sl, msk);
    init_state<<<(NROWS * KX + 255) / 256, 256, 0, stream>>>(hXh, scores, solvedf, lossacc);

    for (int t = 0; t < 6; ++t) {
        // h = X @ W0 + b0 + W0[286+t]  (hints exact in bf16 -> 2-pass GEMM)
        gemm_bf16x2<false><<<dim3(MBLK, NP / 64), 256, 0, stream>>>(
            hXh, nullptr, KX, B0Th, B0Tl, KX, hraw, NP, b0p, w0t + t * NP, KX / 32, pS, pS2);
        for (int l = 0; l < 4; ++l) {
            bn_apply_f<<<dim3(MBLK, NP / 128), 256, 0, stream>>>(
                hraw, pS, pS2, gammas + (size_t)l * H, betas + (size_t)l * H, hAh, hAl);
            if (l < 3) {
                gemm_bf16x2<true><<<dim3(MBLK, NP / 64), 256, 0, stream>>>(
                    hAh, hAl, NP, WhTh + (size_t)l * NP * NP, WhTl + (size_t)l * NP * NP, NP,
                    hraw, NP, bhp + l * NP, nullptr, NP / 32, pS, pS2);
            } else {
                gemm_bf16x2<true><<<dim3(MBLK, OCP / 64), 256, 0, stream>>>(
                    hAh, hAl, NP, BoTh, BoTl, NP, ybuf, OCP, boutp, nullptr, NP / 32,
                    nullptr, nullptr);
            }
        }
        post_turn<<<NROWS / 4, 256, 0, stream>>>(ybuf, glp, gl, sl, msk, hXh, scores, solvedf,
                                                 lossacc, gm, dout, t);
    }
    final_reduce<<<1, 256, 0, stream>>>(scores, solvedf, lossacc, dout);
}

// Round 7
// 1694.638 us; speedup vs baseline: 1.7416x; 1.7416x over previous
//
#include <hip/hip_runtime.h>

#define NROWS 8192
#define NG    12972
#define H     1000
#define NP    1024   // padded hidden width
#define KX    288    // padded hints width (multiple of 32)
#define OCP   256    // padded output cols
#define OC    130
#define EPSBN 1e-5f
#define MBLK  (NROWS / 128)   // 64 row-blocks => 64 stat partials

typedef __attribute__((ext_vector_type(8))) _Float16 f16x8;
typedef __attribute__((ext_vector_type(4))) float f32x4;

__device__ __forceinline__ float lrelu(float x) { return x >= 0.f ? x : 0.2f * x; }

// ---------------- prep: transpose fp32 -> fp16, B^T layout ----------------
// dst[n][k] = src[k][n] for k<R, n<C, else 0. dst dims [Cp][Rp].
__global__ void transpose_f16(const float* __restrict__ src, int R, int C, int srcStride,
                              _Float16* __restrict__ dst, int Rp, int Cp) {
    __shared__ float tile[32][33];
    int k0 = blockIdx.x * 32;
    int n0 = blockIdx.y * 32;
    int tx = threadIdx.x, ty = threadIdx.y;  // 32 x 8
#pragma unroll
    for (int i = 0; i < 32; i += 8) {
        int k = k0 + ty + i, n = n0 + tx;
        tile[ty + i][tx] = (k < R && n < C) ? src[(size_t)k * srcStride + n] : 0.f;
    }
    __syncthreads();
#pragma unroll
    for (int i = 0; i < 32; i += 8) {
        int n = n0 + ty + i, k = k0 + tx;
        if (n < Cp && k < Rp) dst[(size_t)n * Rp + k] = (_Float16)tile[tx][ty + i];
    }
}

__global__ void prep_bias(const float* __restrict__ W0, const float* __restrict__ b0,
                          const float* __restrict__ bh, const float* __restrict__ bout,
                          float* __restrict__ b0p, float* __restrict__ w0t,
                          float* __restrict__ bhp, float* __restrict__ boutp) {
    int i = blockIdx.x * 256 + threadIdx.x;
    if (i < 1024) { b0p[i] = (i < H) ? b0[i] : 0.f; return; }
    i -= 1024;
    if (i < 6 * 1024) {
        int t = i >> 10, n = i & 1023;
        w0t[i] = (n < H) ? W0[(size_t)(286 + t) * H + n] : 0.f;
        return;
    }
    i -= 6 * 1024;
    if (i < 3 * 1024) {
        int l = i >> 10, n = i & 1023;
        bhp[i] = (n < H) ? bh[l * H + n] : 0.f;
        return;
    }
    i -= 3 * 1024;
    if (i < OCP) { boutp[i] = (i < OC) ? bout[i] : 0.f; }
}

// gl: letters (for hint update). glp: packed softmax offsets letter*5+p (5 bytes in uint2).
__global__ void prep_guess_letters(const float* __restrict__ gm, unsigned char* __restrict__ gl,
                                   uint2* __restrict__ glp) {
    int g = blockIdx.x * blockDim.x + threadIdx.x;
    if (g >= NG) return;
    unsigned off[5];
    for (int p = 0; p < 5; ++p) {
        int letter = 0;
        for (int c = 0; c < 26; ++c)
            if (gm[(size_t)g * 130 + c * 5 + p] > 0.5f) { letter = c; break; }
        gl[g * 8 + p] = (unsigned char)letter;
        off[p] = (unsigned)(letter * 5 + p);
    }
    gl[g * 8 + 5] = gl[g * 8 + 6] = gl[g * 8 + 7] = 0;
    glp[g] = make_uint2(off[0] | (off[1] << 8) | (off[2] << 16) | (off[3] << 24), off[4]);
}

__global__ void prep_sol_letters(const float* __restrict__ sols, unsigned char* __restrict__ sl,
                                 unsigned int* __restrict__ msk) {
    int r = blockIdx.x * blockDim.x + threadIdx.x;
    if (r >= NROWS) return;
    unsigned int m = 0;
    for (int p = 0; p < 5; ++p) {
        int letter = 0;
        for (int c = 0; c < 26; ++c)
            if (sols[(size_t)r * 130 + c * 5 + p] > 0.5f) { letter = c; break; }
        sl[r * 8 + p] = (unsigned char)letter;
        m |= 1u << letter;
    }
    sl[r * 8 + 5] = sl[r * 8 + 6] = sl[r * 8 + 7] = 0;
    msk[r] = m;
}

__global__ void init_state(unsigned short* __restrict__ hX, float* __restrict__ scores,
                           int* __restrict__ solvedf, float* __restrict__ lossacc) {
    int i = blockIdx.x * blockDim.x + threadIdx.x;
    if (i < NROWS * KX) hX[i] = 0;
    if (i < NROWS) { scores[i] = 7.f; solvedf[i] = 0; }
    if (i == 0) lossacc[0] = 0.f;
}

// ---------------- GEMM fp16: C = A*B^T + bias, fused column stats ----------------
// m97 structure: 128x128 tile, 4 waves (2x2), BK=32, single LDS buffer (16KB),
// global_load_lds width-16 staging, 16 MFMA : 8 ds_read_b128 per wave K-step.
__global__ __launch_bounds__(256, 2) void gemm_f16(
    const _Float16* __restrict__ A, int lda,
    const _Float16* __restrict__ B, int ldb,
    float* __restrict__ C, int ldc,
    const float* __restrict__ bias1, const float* __restrict__ bias2, int kiter,
    float* __restrict__ pS, float* __restrict__ pS2) {
    __shared__ char smem[16384];
    const int tid = threadIdx.x;
    const int lane = tid & 63;
    const int rowBase = blockIdx.x * 128;
    const int colBase = blockIdx.y * 128;
    const int wm = (tid >> 6) & 1;
    const int wn = tid >> 7;

    // staging map: 16B word w = i*256 + tid; w<512 -> A (r=w&127, kb=w>>7);
    // else B word v=w-512 (col=v&127, kb=v>>7). LDS linear by w.
    const _Float16* gsrc[4];
    int ldsuni[4];
#pragma unroll
    for (int i = 0; i < 4; ++i) {
        int w = i * 256 + tid;
        const _Float16* plane;
        int off;
        if (w < 512) {
            int r = w & 127, kb = w >> 7;
            plane = A;
            off = (rowBase + r) * lda + kb * 8;
        } else {
            int v = w - 512;
            int col = v & 127, kb = v >> 7;
            plane = B;
            off = (colBase + col) * ldb + kb * 8;
        }
        gsrc[i] = plane + off;
        ldsuni[i] = (i * 256 + (tid & ~63)) * 16;  // wave-uniform byte base
    }

    f32x4 acc[4][4];
    const f32x4 z = {0.f, 0.f, 0.f, 0.f};
#pragma unroll
    for (int m = 0; m < 4; ++m)
#pragma unroll
        for (int n = 0; n < 4; ++n) acc[m][n] = z;

    const int aro = (lane >> 4) * 2048 + (wm * 64 + (lane & 15)) * 16;
    const int bco = 8192 + (lane >> 4) * 2048 + (wn * 64 + (lane & 15)) * 16;

    for (int t = 0; t < kiter; ++t) {
#pragma unroll
        for (int i = 0; i < 4; ++i)
            __builtin_amdgcn_global_load_lds(
                (const __attribute__((address_space(1))) void*)(gsrc[i] + (size_t)t * 32),
                (__attribute__((address_space(3))) void*)(smem + ldsuni[i]), 16, 0, 0);
        __syncthreads();

        f16x8 a_f[4], b_f[4];
#pragma unroll
        for (int m = 0; m < 4; ++m) a_f[m] = *(const f16x8*)(smem + aro + m * 256);
#pragma unroll
        for (int n = 0; n < 4; ++n) b_f[n] = *(const f16x8*)(smem + bco + n * 256);
#pragma unroll
        for (int m = 0; m < 4; ++m)
#pragma unroll
            for (int n = 0; n < 4; ++n)
                acc[m][n] = __builtin_amdgcn_mfma_f32_16x16x32_f16(a_f[m], b_f[n], acc[m][n], 0, 0, 0);
        __syncthreads();
    }

    // epilogue (smem contents dead; last loop iter ended with __syncthreads)
    float* sS  = (float*)smem;           // [2][128]
    float* sS2 = (float*)smem + 256;     // [2][128]
    const int lane16 = lane & 15, lanehi = lane >> 4;
#pragma unroll
    for (int n = 0; n < 4; ++n) {
        int col = colBase + wn * 64 + n * 16 + lane16;
        float bv = bias1[col] + (bias2 ? bias2[col] : 0.f);
        float s = 0.f, s2 = 0.f;
#pragma unroll
        for (int m = 0; m < 4; ++m) {
            int row0 = rowBase + wm * 64 + m * 16 + lanehi * 4;
#pragma unroll
            for (int r = 0; r < 4; ++r) {
                float cv = acc[m][n][r] + bv;
                C[(size_t)(row0 + r) * ldc + col] = cv;
                s += cv; s2 += cv * cv;
            }
        }
        if (pS) {
            s += __shfl_xor(s, 16);  s += __shfl_xor(s, 32);
            s2 += __shfl_xor(s2, 16); s2 += __shfl_xor(s2, 32);
            if (lanehi == 0) {
                int lcol = wn * 64 + n * 16 + lane16;
                sS[wm * 128 + lcol] = s;
                sS2[wm * 128 + lcol] = s2;
            }
        }
    }
    if (pS) {
        __syncthreads();
        if (tid < 128) {
            int col = colBase + tid;
            pS[(size_t)blockIdx.x * NP + col] = sS[tid] + sS[128 + tid];
            pS2[(size_t)blockIdx.x * NP + col] = sS2[tid] + sS2[128 + tid];
        }
    }
}

// ---------------- fused BN finalize + apply + lrelu + fp16 cast ----------------
// Each block reduces the 64 stat partials for its 128 columns (same fp order as before
// -> bit-identical stats), then applies BN to its 128x128 tile, writing fp16.
__global__ __launch_bounds__(256) void bn_apply_f(
    const float* __restrict__ hraw, const float* __restrict__ pS, const float* __restrict__ pS2,
    const float* __restrict__ gamma, const float* __restrict__ beta,
    _Float16* __restrict__ oh) {
    __shared__ float la[128], lb[128];
    const int tid = threadIdx.x;
    const int rowBase = blockIdx.x * 128;
    const int colBase = blockIdx.y * 128;
    if (tid < 128) {
        int col = colBase + tid;
        float s = 0.f;
        for (int j = 0; j < MBLK; ++j) s += pS[(size_t)j * NP + col];
        la[tid] = s;
    } else {
        int col = colBase + tid - 128;
        float s2 = 0.f;
        for (int j = 0; j < MBLK; ++j) s2 += pS2[(size_t)j * NP + col];
        lb[tid - 128] = s2;
    }
    __syncthreads();
    if (tid < 128) {
        int col = colBase + tid;
        float a = 0.f, b = 0.f;
        if (col < H) {
            float mean = la[tid] * (1.f / NROWS);
            float var = lb[tid] * (1.f / NROWS) - mean * mean;
            float inv = rsqrtf(var + EPSBN);
            a = gamma[col] * inv;
            b = beta[col] - mean * a;
        }
        la[tid] = a;
        lb[tid] = b;
    }
    __syncthreads();
#pragma unroll
    for (int i = 0; i < 16; ++i) {
        int idx = i * 256 + tid;            // 0..4095
        int row = idx >> 5;                 // 32 float4 per row
        int c4 = (idx & 31) * 4;
        const float4 v = *(const float4*)(hraw + (size_t)(rowBase + row) * NP + colBase + c4);
        _Float16 x0 = (_Float16)lrelu(la[c4] * v.x + lb[c4]);
        _Float16 x1 = (_Float16)lrelu(la[c4 + 1] * v.y + lb[c4 + 1]);
        _Float16 x2 = (_Float16)lrelu(la[c4 + 2] * v.z + lb[c4 + 2]);
        _Float16 x3 = (_Float16)lrelu(la[c4 + 3] * v.w + lb[c4 + 3]);
        f16x8 pack0;  // only 4 used; store as 8B
        ushort4 outv;
        outv.x = __builtin_bit_cast(unsigned short, x0);
        outv.y = __builtin_bit_cast(unsigned short, x1);
        outv.z = __builtin_bit_cast(unsigned short, x2);
        outv.w = __builtin_bit_cast(unsigned short, x3);
        (void)pack0;
        *(ushort4*)((unsigned short*)oh + (size_t)(rowBase + row) * NP + colBase + c4) = outv;
    }
}

// ---------------- fused per-turn tail: softmax + loss + vocab argmax + hints ----------------
__global__ __launch_bounds__(256) void post_turn(
    const float* __restrict__ ybuf, const uint2* __restrict__ glp,
    const unsigned char* __restrict__ gl, const unsigned char* __restrict__ sl,
    const unsigned int* __restrict__ msk, _Float16* __restrict__ hX,
    float* __restrict__ scores, int* __restrict__ solvedf, float* __restrict__ lossacc,
    const float* __restrict__ gm, float* __restrict__ dout, int turn) {
    const int r0 = blockIdx.x * 4;
    __shared__ float4 pk[130];           // pk[c] = {row0[c], row1[c], row2[c], row3[c]} softmax probs
    __shared__ float lcon[20];
    __shared__ float wb[4][4];
    __shared__ int wi[4][4];
    __shared__ int fidx[4];
    const int tid = threadIdx.x;

    if (tid < 20) {
        int row = tid / 5, p = tid - row * 5;
        const float* yr = ybuf + (size_t)(r0 + row) * OCP + p;
        float m = -1e30f;
#pragma unroll
        for (int c = 0; c < 26; ++c) m = fmaxf(m, yr[c * 5]);
        float e[26];
        float s = 0.f;
#pragma unroll
        for (int c = 0; c < 26; ++c) { e[c] = expf(yr[c * 5] - m); s += e[c]; }
        float inv = 1.f / s;
#pragma unroll
        for (int c = 0; c < 26; ++c) ((float*)&pk[c * 5 + p])[row] = e[c] * inv;
        lcon[tid] = logf(s) + m - yr[sl[(size_t)(r0 + row) * 8 + p] * 5];
    }
    __syncthreads();

    // vocab scan: 4 rows in parallel per thread
    float b0 = -1e30f, b1 = -1e30f, b2 = -1e30f, b3 = -1e30f;
    int i0 = 1 << 30, i1 = 1 << 30, i2 = 1 << 30, i3 = 1 << 30;
    for (int g = tid; g < NG; g += 256) {
        uint2 w = glp[g];
        float4 s0 = pk[w.x & 255];
        float4 s1 = pk[(w.x >> 8) & 255];
        float4 s2 = pk[(w.x >> 16) & 255];
        float4 s3 = pk[w.x >> 24];
        float4 s4 = pk[w.y & 255];
        // same left-assoc add order as reference gather
        float vx = s0.x + s1.x; vx += s2.x; vx += s3.x; vx += s4.x;
        float vy = s0.y + s1.y; vy += s2.y; vy += s3.y; vy += s4.y;
        float vz = s0.z + s1.z; vz += s2.z; vz += s3.z; vz += s4.z;
        float vw = s0.w + s1.w; vw += s2.w; vw += s3.w; vw += s4.w;
        if (vx > b0) { b0 = vx; i0 = g; }
        if (vy > b1) { b1 = vy; i1 = g; }
        if (vz > b2) { b2 = vz; i2 = g; }
        if (vw > b3) { b3 = vw; i3 = g; }
    }
#pragma unroll
    for (int off = 1; off < 64; off <<= 1) {
        float o; int oi;
        o = __shfl_xor(b0, off); oi = __shfl_xor(i0, off);
        if (o > b0 || (o == b0 && oi < i0)) { b0 = o; i0 = oi; }
        o = __shfl_xor(b1, off); oi = __shfl_xor(i1, off);
        if (o > b1 || (o == b1 && oi < i1)) { b1 = o; i1 = oi; }
        o = __shfl_xor(b2, off); oi = __shfl_xor(i2, off);
        if (o > b2 || (o == b2 && oi < i2)) { b2 = o; i2 = oi; }
        o = __shfl_xor(b3, off); oi = __shfl_xor(i3, off);
        if (o > b3 || (o == b3 && oi < i3)) { b3 = o; i3 = oi; }
    }
    const int wid = tid >> 6, lane = tid & 63;
    if (lane == 0) {
        wb[wid][0] = b0; wi[wid][0] = i0;
        wb[wid][1] = b1; wi[wid][1] = i1;
        wb[wid][2] = b2; wi[wid][2] = i2;
        wb[wid][3] = b3; wi[wid][3] = i3;
    }
    __syncthreads();

    if (tid < 4) {
        float b = wb[0][tid]; int x = wi[0][tid];
#pragma unroll
        for (int wv = 1; wv < 4; ++wv)
            if (wb[wv][tid] > b || (wb[wv][tid] == b && wi[wv][tid] < x)) { b = wb[wv][tid]; x = wi[wv][tid]; }
        fidx[tid] = x;
        // hints / scores / solved for row r0+tid
        int r = r0 + tid;
        const unsigned char* q = gl + x * 8;
        const unsigned char* so = sl + (size_t)r * 8;
        unsigned int mk = msk[r];
        _Float16* hrow = hX + (size_t)r * KX;
        int allg = 1;
#pragma unroll
        for (int p = 0; p < 5; ++p) {
            int g = q[p];
            int off;
            if (g == so[p]) {
                off = g * 5 + p;  // green
            } else {
                allg = 0;
                off = ((mk >> g) & 1u) ? (130 + g * 5 + p) : (260 + g);  // yellow : black
            }
            hrow[off] = (_Float16)((float)hrow[off] + 1.f);
        }
        solvedf[r] = allg;
        if (allg && scores[r] > (float)(turn + 1)) scores[r] = (float)(turn + 1);
    }
    if (tid == 8 && turn >= 1) {
        float t = 0.f;
#pragma unroll
        for (int j = 0; j < 20; ++j) t += lcon[j];
        atomicAdd(lossacc, t * (1.f / (NROWS * 5)));
    }
    __syncthreads();
    if (turn == 0 && blockIdx.x == 0 && tid >= 64 && tid < 64 + OC) {
        dout[3 + tid - 64] = gm[(size_t)fidx[0] * OC + (tid - 64)];
    }
}

__global__ void final_reduce(const float* __restrict__ scores, const int* __restrict__ solvedf,
                             const float* __restrict__ lossacc, float* __restrict__ dout) {
    __shared__ float rs[256];
    __shared__ int ri[256];
    int tid = threadIdx.x;
    float s = 0.f;
    int c = 0;
    for (int r = tid; r < NROWS; r += 256) { s += scores[r]; c += solvedf[r]; }
    rs[tid] = s; ri[tid] = c;
    __syncthreads();
    for (int off = 128; off > 0; off >>= 1) {
        if (tid < off) { rs[tid] += rs[tid + off]; ri[tid] += ri[tid + off]; }
        __syncthreads();
    }
    if (tid == 0) {
        dout[0] = lossacc[0];
        dout[1] = rs[0];
        dout[2] = (float)ri[0];
    }
}

// ---------------- launch ----------------
extern "C" void kernel_launch(void* const* d_in, const int* in_sizes, int n_in,
                              void* d_out, int out_size, void* d_ws, size_t ws_size,
                              hipStream_t stream) {
    const float* sols   = (const float*)d_in[0];
    const float* gm     = (const float*)d_in[1];
    const float* W0     = (const float*)d_in[2];
    const float* b0     = (const float*)d_in[3];
    const float* gammas = (const float*)d_in[4];
    const float* betas  = (const float*)d_in[5];
    const float* Wh     = (const float*)d_in[6];
    const float* bh     = (const float*)d_in[7];
    const float* Wout   = (const float*)d_in[8];
    const float* bout   = (const float*)d_in[9];
    float* dout = (float*)d_out;

    char* p = (char*)d_ws;
    auto alloc = [&](size_t bytes) { void* r = (void*)p; p += (bytes + 255) & ~(size_t)255; return r; };
    _Float16* hX  = (_Float16*)alloc((size_t)NROWS * KX * 2);
    _Float16* hA  = (_Float16*)alloc((size_t)NROWS * NP * 2);
    float* hraw   = (float*)alloc((size_t)NROWS * NP * 4);
    float* ybuf   = hraw;   // alias: hraw dead when ybuf written (out layer)
    _Float16* B0T = (_Float16*)alloc((size_t)NP * KX * 2);
    _Float16* WhT = (_Float16*)alloc((size_t)3 * NP * NP * 2);
    _Float16* BoT = (_Float16*)alloc((size_t)OCP * NP * 2);
    float* b0p   = (float*)alloc(NP * 4);
    float* w0t   = (float*)alloc(6 * NP * 4);
    float* bhp   = (float*)alloc(3 * NP * 4);
    float* boutp = (float*)alloc(OCP * 4);
    float* pS    = (float*)alloc((size_t)MBLK * NP * 4);
    float* pS2   = (float*)alloc((size_t)MBLK * NP * 4);
    float* scores  = (float*)alloc(NROWS * 4);
    float* lossacc = (float*)alloc(256);
    int* solvedf = (int*)alloc(NROWS * 4);
    unsigned char* gl = (unsigned char*)alloc(NG * 8);
    uint2* glp = (uint2*)alloc(NG * 8);
    unsigned char* sl = (unsigned char*)alloc(NROWS * 8);
    unsigned int* msk = (unsigned int*)alloc(NROWS * 4);

    // ---- prep ----
    transpose_f16<<<dim3(KX / 32, NP / 32), dim3(32, 8), 0, stream>>>(W0, 286, H, H, B0T, KX, NP);
    for (int l = 0; l < 3; ++l)
        transpose_f16<<<dim3(NP / 32, NP / 32), dim3(32, 8), 0, stream>>>(
            Wh + (size_t)l * H * H, H, H, H, WhT + (size_t)l * NP * NP, NP, NP);
    transpose_f16<<<dim3(NP / 32, OCP / 32), dim3(32, 8), 0, stream>>>(Wout, H, OC, OC, BoT, NP, OCP);
    prep_bias<<<41, 256, 0, stream>>>(W0, b0, bh, bout, b0p, w0t, bhp, boutp);
    prep_guess_letters<<<(NG + 255) / 256, 256, 0, stream>>>(gm, gl, glp);
    prep_sol_letters<<<(NROWS + 255) / 256, 256, 0, stream>>>(sols, sl, msk);
    init_state<<<(NROWS * KX + 255) / 256, 256, 0, stream>>>((unsigned short*)hX, scores, solvedf, lossacc);

    for (int t = 0; t < 6; ++t) {
        // h = X @ W0 + b0 + W0[286+t]  (turn one-hot folded into bias2)
        gemm_f16<<<dim3(MBLK, NP / 128), 256, 0, stream>>>(
            hX, KX, B0T, KX, hraw, NP, b0p, w0t + t * NP, KX / 32, pS, pS2);
        for (int l = 0; l < 4; ++l) {
            bn_apply_f<<<dim3(MBLK, NP / 128), 256, 0, stream>>>(
                hraw, pS, pS2, gammas + (size_t)l * H, betas + (size_t)l * H, hA);
            if (l < 3) {
                gemm_f16<<<dim3(MBLK, NP / 128), 256, 0, stream>>>(
                    hA, NP, WhT + (size_t)l * NP * NP, NP, hraw, NP, bhp + l * NP, nullptr,
                    NP / 32, pS, pS2);
            } else {
                gemm_f16<<<dim3(MBLK, OCP / 128), 256, 0, stream>>>(
                    hA, NP, BoT, NP, ybuf, OCP, boutp, nullptr, NP / 32, nullptr, nullptr);
            }
        }
        post_turn<<<NROWS / 4, 256, 0, stream>>>(ybuf, glp, gl, sl, msk, hX, scores, solvedf,
                                                 lossacc, gm, dout, t);
    }
    final_reduce<<<1, 256, 0, stream>>>(scores, solvedf, lossacc, dout);
}

// Round 8
// 1588.575 us; speedup vs baseline: 1.8579x; 1.0668x over previous
//
#include <hip/hip_runtime.h>

#define NROWS 8192
#define NG    12972
#define H     1000
#define NP    1024   // padded hidden width
#define KX    288    // padded hints width (multiple of 32)
#define OCP   256    // padded output cols
#define OC    130
#define EPSBN 1e-5f
#define MBLK  (NROWS / 128)   // 64 row-blocks => 64 stat partials

typedef __attribute__((ext_vector_type(8))) _Float16 f16x8;
typedef __attribute__((ext_vector_type(8))) unsigned short u16x8;
typedef __attribute__((ext_vector_type(4))) float f32x4;

__device__ __forceinline__ float lrelu(float x) { return x >= 0.f ? x : 0.2f * x; }

// ---------------- prep: transpose fp32 -> fp16, B^T layout ----------------
__global__ void transpose_f16(const float* __restrict__ src, int R, int C, int srcStride,
                              _Float16* __restrict__ dst, int Rp, int Cp) {
    __shared__ float tile[32][33];
    int k0 = blockIdx.x * 32;
    int n0 = blockIdx.y * 32;
    int tx = threadIdx.x, ty = threadIdx.y;  // 32 x 8
#pragma unroll
    for (int i = 0; i < 32; i += 8) {
        int k = k0 + ty + i, n = n0 + tx;
        tile[ty + i][tx] = (k < R && n < C) ? src[(size_t)k * srcStride + n] : 0.f;
    }
    __syncthreads();
#pragma unroll
    for (int i = 0; i < 32; i += 8) {
        int n = n0 + ty + i, k = k0 + tx;
        if (n < Cp && k < Rp) dst[(size_t)n * Rp + k] = (_Float16)tile[tx][ty + i];
    }
}

__global__ void prep_bias(const float* __restrict__ W0, const float* __restrict__ b0,
                          const float* __restrict__ bh, const float* __restrict__ bout,
                          float* __restrict__ b0p, float* __restrict__ w0t,
                          float* __restrict__ bhp, float* __restrict__ boutp) {
    int i = blockIdx.x * 256 + threadIdx.x;
    if (i < 1024) { b0p[i] = (i < H) ? b0[i] : 0.f; return; }
    i -= 1024;
    if (i < 6 * 1024) {
        int t = i >> 10, n = i & 1023;
        w0t[i] = (n < H) ? W0[(size_t)(286 + t) * H + n] : 0.f;
        return;
    }
    i -= 6 * 1024;
    if (i < 3 * 1024) {
        int l = i >> 10, n = i & 1023;
        bhp[i] = (n < H) ? bh[l * H + n] : 0.f;
        return;
    }
    i -= 3 * 1024;
    if (i < OCP) { boutp[i] = (i < OC) ? bout[i] : 0.f; }
}

// gl: letters (for hint update). glp: packed softmax offsets letter*5+p (5 bytes in uint2).
__global__ void prep_guess_letters(const float* __restrict__ gm, unsigned char* __restrict__ gl,
                                   uint2* __restrict__ glp) {
    int g = blockIdx.x * blockDim.x + threadIdx.x;
    if (g >= NG) return;
    unsigned off[5];
    for (int p = 0; p < 5; ++p) {
        int letter = 0;
        for (int c = 0; c < 26; ++c)
            if (gm[(size_t)g * 130 + c * 5 + p] > 0.5f) { letter = c; break; }
        gl[g * 8 + p] = (unsigned char)letter;
        off[p] = (unsigned)(letter * 5 + p);
    }
    gl[g * 8 + 5] = gl[g * 8 + 6] = gl[g * 8 + 7] = 0;
    glp[g] = make_uint2(off[0] | (off[1] << 8) | (off[2] << 16) | (off[3] << 24), off[4]);
}

__global__ void prep_sol_letters(const float* __restrict__ sols, unsigned char* __restrict__ sl,
                                 unsigned int* __restrict__ msk) {
    int r = blockIdx.x * blockDim.x + threadIdx.x;
    if (r >= NROWS) return;
    unsigned int m = 0;
    for (int p = 0; p < 5; ++p) {
        int letter = 0;
        for (int c = 0; c < 26; ++c)
            if (sols[(size_t)r * 130 + c * 5 + p] > 0.5f) { letter = c; break; }
        sl[r * 8 + p] = (unsigned char)letter;
        m |= 1u << letter;
    }
    sl[r * 8 + 5] = sl[r * 8 + 6] = sl[r * 8 + 7] = 0;
    msk[r] = m;
}

__global__ void init_state(unsigned short* __restrict__ hX, float* __restrict__ scores,
                           int* __restrict__ solvedf, float* __restrict__ lossacc) {
    int i = blockIdx.x * blockDim.x + threadIdx.x;
    if (i < NROWS * KX) hX[i] = 0;
    if (i < NROWS) { scores[i] = 7.f; solvedf[i] = 0; }
    if (i == 0) lossacc[0] = 0.f;
}

// ---------------- GEMM fp16: C = A*B^T + bias, fused column stats ----------------
// m97 structure: 128x128 tile, 4 waves (2x2), BK=32, single LDS buffer (16KB),
// global_load_lds width-16 staging, 16 MFMA : 8 ds_read_b128 per wave K-step.
// HALF_C: write C as fp16 (stats still from fp32 acc+bias -> BN coefs bit-identical).
template <bool HALF_C>
__global__ __launch_bounds__(256, 2) void gemm_f16(
    const _Float16* __restrict__ A, int lda,
    const _Float16* __restrict__ B, int ldb,
    void* __restrict__ Cv, int ldc,
    const float* __restrict__ bias1, const float* __restrict__ bias2, int kiter,
    float* __restrict__ pS, float* __restrict__ pS2) {
    __shared__ char smem[16384];
    const int tid = threadIdx.x;
    const int lane = tid & 63;
    const int rowBase = blockIdx.x * 128;
    const int colBase = blockIdx.y * 128;
    const int wm = (tid >> 6) & 1;
    const int wn = tid >> 7;

    const _Float16* gsrc[4];
    int ldsuni[4];
#pragma unroll
    for (int i = 0; i < 4; ++i) {
        int w = i * 256 + tid;
        const _Float16* plane;
        int off;
        if (w < 512) {
            int r = w & 127, kb = w >> 7;
            plane = A;
            off = (rowBase + r) * lda + kb * 8;
        } else {
            int v = w - 512;
            int col = v & 127, kb = v >> 7;
            plane = B;
            off = (colBase + col) * ldb + kb * 8;
        }
        gsrc[i] = plane + off;
        ldsuni[i] = (i * 256 + (tid & ~63)) * 16;  // wave-uniform byte base
    }

    f32x4 acc[4][4];
    const f32x4 z = {0.f, 0.f, 0.f, 0.f};
#pragma unroll
    for (int m = 0; m < 4; ++m)
#pragma unroll
        for (int n = 0; n < 4; ++n) acc[m][n] = z;

    const int aro = (lane >> 4) * 2048 + (wm * 64 + (lane & 15)) * 16;
    const int bco = 8192 + (lane >> 4) * 2048 + (wn * 64 + (lane & 15)) * 16;

    for (int t = 0; t < kiter; ++t) {
#pragma unroll
        for (int i = 0; i < 4; ++i)
            __builtin_amdgcn_global_load_lds(
                (const __attribute__((address_space(1))) void*)(gsrc[i] + (size_t)t * 32),
                (__attribute__((address_space(3))) void*)(smem + ldsuni[i]), 16, 0, 0);
        __syncthreads();

        f16x8 a_f[4], b_f[4];
#pragma unroll
        for (int m = 0; m < 4; ++m) a_f[m] = *(const f16x8*)(smem + aro + m * 256);
#pragma unroll
        for (int n = 0; n < 4; ++n) b_f[n] = *(const f16x8*)(smem + bco + n * 256);
#pragma unroll
        for (int m = 0; m < 4; ++m)
#pragma unroll
            for (int n = 0; n < 4; ++n)
                acc[m][n] = __builtin_amdgcn_mfma_f32_16x16x32_f16(a_f[m], b_f[n], acc[m][n], 0, 0, 0);
        __syncthreads();
    }

    // epilogue (smem contents dead; last loop iter ended with __syncthreads)
    float* sS  = (float*)smem;           // [2][128]
    float* sS2 = (float*)smem + 256;     // [2][128]
    const int lane16 = lane & 15, lanehi = lane >> 4;
#pragma unroll
    for (int n = 0; n < 4; ++n) {
        int col = colBase + wn * 64 + n * 16 + lane16;
        float bv = bias1[col] + (bias2 ? bias2[col] : 0.f);
        float s = 0.f, s2 = 0.f;
#pragma unroll
        for (int m = 0; m < 4; ++m) {
            int row0 = rowBase + wm * 64 + m * 16 + lanehi * 4;
#pragma unroll
            for (int r = 0; r < 4; ++r) {
                float cv = acc[m][n][r] + bv;
                if constexpr (HALF_C)
                    ((_Float16*)Cv)[(size_t)(row0 + r) * ldc + col] = (_Float16)cv;
                else
                    ((float*)Cv)[(size_t)(row0 + r) * ldc + col] = cv;
                s += cv; s2 += cv * cv;
            }
        }
        if (pS) {
            s += __shfl_xor(s, 16);  s += __shfl_xor(s, 32);
            s2 += __shfl_xor(s2, 16); s2 += __shfl_xor(s2, 32);
            if (lanehi == 0) {
                int lcol = wn * 64 + n * 16 + lane16;
                sS[wm * 128 + lcol] = s;
                sS2[wm * 128 + lcol] = s2;
            }
        }
    }
    if (pS) {
        __syncthreads();
        if (tid < 128) {
            int col = colBase + tid;
            pS[(size_t)blockIdx.x * NP + col] = sS[tid] + sS[128 + tid];
            pS2[(size_t)blockIdx.x * NP + col] = sS2[tid] + sS2[128 + tid];
        }
    }
}

// ---------------- fused BN finalize + apply + lrelu (fp16 in, fp16 out) ----------------
// Each block reduces the 64 stat partials for its 128 columns (same fp order as before
// -> bit-identical BN coefs), then applies to its 128x128 tile of hraw (fp16).
__global__ __launch_bounds__(256) void bn_apply_f(
    const _Float16* __restrict__ hraw, const float* __restrict__ pS, const float* __restrict__ pS2,
    const float* __restrict__ gamma, const float* __restrict__ beta,
    _Float16* __restrict__ oh) {
    __shared__ float la[128], lb[128];
    const int tid = threadIdx.x;
    const int rowBase = blockIdx.x * 128;
    const int colBase = blockIdx.y * 128;
    if (tid < 128) {
        int col = colBase + tid;
        float s = 0.f;
        for (int j = 0; j < MBLK; ++j) s += pS[(size_t)j * NP + col];
        la[tid] = s;
    } else {
        int col = colBase + tid - 128;
        float s2 = 0.f;
        for (int j = 0; j < MBLK; ++j) s2 += pS2[(size_t)j * NP + col];
        lb[tid - 128] = s2;
    }
    __syncthreads();
    if (tid < 128) {
        int col = colBase + tid;
        float a = 0.f, b = 0.f;
        if (col < H) {
            float mean = la[tid] * (1.f / NROWS);
            float var = lb[tid] * (1.f / NROWS) - mean * mean;
            float inv = rsqrtf(var + EPSBN);
            a = gamma[col] * inv;
            b = beta[col] - mean * a;
        }
        la[tid] = a;
        lb[tid] = b;
    }
    __syncthreads();
    // c8 depends only on tid -> hoist BN coefs to registers
    const int c8 = (tid & 15) * 8;
    float ar[8], br[8];
#pragma unroll
    for (int j = 0; j < 8; ++j) { ar[j] = la[c8 + j]; br[j] = lb[c8 + j]; }
#pragma unroll
    for (int i = 0; i < 8; ++i) {
        int row = i * 16 + (tid >> 4);
        const u16x8 v = *(const u16x8*)(hraw + (size_t)(rowBase + row) * NP + colBase + c8);
        u16x8 o;
#pragma unroll
        for (int j = 0; j < 8; ++j) {
            float x = (float)__builtin_bit_cast(_Float16, (unsigned short)v[j]);
            o[j] = __builtin_bit_cast(unsigned short, (_Float16)lrelu(ar[j] * x + br[j]));
        }
        *(u16x8*)((unsigned short*)oh + (size_t)(rowBase + row) * NP + colBase + c8) = o;
    }
}

// ---------------- fused per-turn tail: softmax + loss + vocab argmax + hints ----------------
// SoA prob tables pk[row][132]: random b32 gathers spread over all 32 banks (vs the old
// float4 AoS whose bank phase was c%8 -> ~8-way conflicts, 7.85M conflict cycles).
__global__ __launch_bounds__(256) void post_turn(
    const float* __restrict__ ybuf, const uint2* __restrict__ glp,
    const unsigned char* __restrict__ gl, const unsigned char* __restrict__ sl,
    const unsigned int* __restrict__ msk, _Float16* __restrict__ hX,
    float* __restrict__ scores, int* __restrict__ solvedf, float* __restrict__ lossacc,
    const float* __restrict__ gm, float* __restrict__ dout, int turn) {
    const int r0 = blockIdx.x * 4;
    __shared__ float pk[4][132];         // SoA: pk[row][letterOffset]
    __shared__ float lcon[20];
    __shared__ float wb[4][4];
    __shared__ int wi[4][4];
    __shared__ int fidx[4];
    const int tid = threadIdx.x;

    if (tid < 20) {
        int row = tid / 5, p = tid - row * 5;
        const float* yr = ybuf + (size_t)(r0 + row) * OCP + p;
        float m = -1e30f;
#pragma unroll
        for (int c = 0; c < 26; ++c) m = fmaxf(m, yr[c * 5]);
        float e[26];
        float s = 0.f;
#pragma unroll
        for (int c = 0; c < 26; ++c) { e[c] = expf(yr[c * 5] - m); s += e[c]; }
        float inv = 1.f / s;
#pragma unroll
        for (int c = 0; c < 26; ++c) pk[row][c * 5 + p] = e[c] * inv;
        lcon[tid] = logf(s) + m - yr[sl[(size_t)(r0 + row) * 8 + p] * 5];
    }
    __syncthreads();

    // vocab scan: 4 rows per thread, words strided over 256 threads
    float b0 = -1e30f, b1 = -1e30f, b2 = -1e30f, b3 = -1e30f;
    int i0 = 1 << 30, i1 = 1 << 30, i2 = 1 << 30, i3 = 1 << 30;
    for (int g = tid; g < NG; g += 256) {
        uint2 w = glp[g];
        int o0 = w.x & 255, o1 = (w.x >> 8) & 255, o2 = (w.x >> 16) & 255,
            o3 = w.x >> 24, o4 = w.y & 255;
        // same left-assoc add order as reference gather
        float vx = pk[0][o0] + pk[0][o1]; vx += pk[0][o2]; vx += pk[0][o3]; vx += pk[0][o4];
        float vy = pk[1][o0] + pk[1][o1]; vy += pk[1][o2]; vy += pk[1][o3]; vy += pk[1][o4];
        float vz = pk[2][o0] + pk[2][o1]; vz += pk[2][o2]; vz += pk[2][o3]; vz += pk[2][o4];
        float vw = pk[3][o0] + pk[3][o1]; vw += pk[3][o2]; vw += pk[3][o3]; vw += pk[3][o4];
        if (vx > b0) { b0 = vx; i0 = g; }
        if (vy > b1) { b1 = vy; i1 = g; }
        if (vz > b2) { b2 = vz; i2 = g; }
        if (vw > b3) { b3 = vw; i3 = g; }
    }
#pragma unroll
    for (int off = 1; off < 64; off <<= 1) {
        float o; int oi;
        o = __shfl_xor(b0, off); oi = __shfl_xor(i0, off);
        if (o > b0 || (o == b0 && oi < i0)) { b0 = o; i0 = oi; }
        o = __shfl_xor(b1, off); oi = __shfl_xor(i1, off);
        if (o > b1 || (o == b1 && oi < i1)) { b1 = o; i1 = oi; }
        o = __shfl_xor(b2, off); oi = __shfl_xor(i2, off);
        if (o > b2 || (o == b2 && oi < i2)) { b2 = o; i2 = oi; }
        o = __shfl_xor(b3, off); oi = __shfl_xor(i3, off);
        if (o > b3 || (o == b3 && oi < i3)) { b3 = o; i3 = oi; }
    }
    const int wid = tid >> 6, lane = tid & 63;
    if (lane == 0) {
        wb[wid][0] = b0; wi[wid][0] = i0;
        wb[wid][1] = b1; wi[wid][1] = i1;
        wb[wid][2] = b2; wi[wid][2] = i2;
        wb[wid][3] = b3; wi[wid][3] = i3;
    }
    __syncthreads();

    if (tid < 4) {
        float b = wb[0][tid]; int x = wi[0][tid];
#pragma unroll
        for (int wv = 1; wv < 4; ++wv)
            if (wb[wv][tid] > b || (wb[wv][tid] == b && wi[wv][tid] < x)) { b = wb[wv][tid]; x = wi[wv][tid]; }
        fidx[tid] = x;
        // hints / scores / solved for row r0+tid
        int r = r0 + tid;
        const unsigned char* q = gl + x * 8;
        const unsigned char* so = sl + (size_t)r * 8;
        unsigned int mk = msk[r];
        _Float16* hrow = hX + (size_t)r * KX;
        int allg = 1;
#pragma unroll
        for (int p = 0; p < 5; ++p) {
            int g = q[p];
            int off;
            if (g == so[p]) {
                off = g * 5 + p;  // green
            } else {
                allg = 0;
                off = ((mk >> g) & 1u) ? (130 + g * 5 + p) : (260 + g);  // yellow : black
            }
            hrow[off] = (_Float16)((float)hrow[off] + 1.f);
        }
        solvedf[r] = allg;
        if (allg && scores[r] > (float)(turn + 1)) scores[r] = (float)(turn + 1);
    }
    if (tid == 8 && turn >= 1) {
        float t = 0.f;
#pragma unroll
        for (int j = 0; j < 20; ++j) t += lcon[j];
        atomicAdd(lossacc, t * (1.f / (NROWS * 5)));
    }
    __syncthreads();
    if (turn == 0 && blockIdx.x == 0 && tid >= 64 && tid < 64 + OC) {
        dout[3 + tid - 64] = gm[(size_t)fidx[0] * OC + (tid - 64)];
    }
}

__global__ void final_reduce(const float* __restrict__ scores, const int* __restrict__ solvedf,
                             const float* __restrict__ lossacc, float* __restrict__ dout) {
    __shared__ float rs[256];
    __shared__ int ri[256];
    int tid = threadIdx.x;
    float s = 0.f;
    int c = 0;
    for (int r = tid; r < NROWS; r += 256) { s += scores[r]; c += solvedf[r]; }
    rs[tid] = s; ri[tid] = c;
    __syncthreads();
    for (int off = 128; off > 0; off >>= 1) {
        if (tid < off) { rs[tid] += rs[tid + off]; ri[tid] += ri[tid + off]; }
        __syncthreads();
    }
    if (tid == 0) {
        dout[0] = lossacc[0];
        dout[1] = rs[0];
        dout[2] = (float)ri[0];
    }
}

// ---------------- launch ----------------
extern "C" void kernel_launch(void* const* d_in, const int* in_sizes, int n_in,
                              void* d_out, int out_size, void* d_ws, size_t ws_size,
                              hipStream_t stream) {
    const float* sols   = (const float*)d_in[0];
    const float* gm     = (const float*)d_in[1];
    const float* W0     = (const float*)d_in[2];
    const float* b0     = (const float*)d_in[3];
    const float* gammas = (const float*)d_in[4];
    const float* betas  = (const float*)d_in[5];
    const float* Wh     = (const float*)d_in[6];
    const float* bh     = (const float*)d_in[7];
    const float* Wout   = (const float*)d_in[8];
    const float* bout   = (const float*)d_in[9];
    float* dout = (float*)d_out;

    char* p = (char*)d_ws;
    auto alloc = [&](size_t bytes) { void* r = (void*)p; p += (bytes + 255) & ~(size_t)255; return r; };
    _Float16* hX   = (_Float16*)alloc((size_t)NROWS * KX * 2);
    _Float16* hA   = (_Float16*)alloc((size_t)NROWS * NP * 2);
    _Float16* hraw = (_Float16*)alloc((size_t)NROWS * NP * 2);
    float* ybuf    = (float*)alloc((size_t)NROWS * OCP * 4);
    _Float16* B0T = (_Float16*)alloc((size_t)NP * KX * 2);
    _Float16* WhT = (_Float16*)alloc((size_t)3 * NP * NP * 2);
    _Float16* BoT = (_Float16*)alloc((size_t)OCP * NP * 2);
    float* b0p   = (float*)alloc(NP * 4);
    float* w0t   = (float*)alloc(6 * NP * 4);
    float* bhp   = (float*)alloc(3 * NP * 4);
    float* boutp = (float*)alloc(OCP * 4);
    float* pS    = (float*)alloc((size_t)MBLK * NP * 4);
    float* pS2   = (float*)alloc((size_t)MBLK * NP * 4);
    float* scores  = (float*)alloc(NROWS * 4);
    float* lossacc = (float*)alloc(256);
    int* solvedf = (int*)alloc(NROWS * 4);
    unsigned char* gl = (unsigned char*)alloc(NG * 8);
    uint2* glp = (uint2*)alloc(NG * 8);
    unsigned char* sl = (unsigned char*)alloc(NROWS * 8);
    unsigned int* msk = (unsigned int*)alloc(NROWS * 4);

    // ---- prep ----
    transpose_f16<<<dim3(KX / 32, NP / 32), dim3(32, 8), 0, stream>>>(W0, 286, H, H, B0T, KX, NP);
    for (int l = 0; l < 3; ++l)
        transpose_f16<<<dim3(NP / 32, NP / 32), dim3(32, 8), 0, stream>>>(
            Wh + (size_t)l * H * H, H, H, H, WhT + (size_t)l * NP * NP, NP, NP);
    transpose_f16<<<dim3(NP / 32, OCP / 32), dim3(32, 8), 0, stream>>>(Wout, H, OC, OC, BoT, NP, OCP);
    prep_bias<<<41, 256, 0, stream>>>(W0, b0, bh, bout, b0p, w0t, bhp, boutp);
    prep_guess_letters<<<(NG + 255) / 256, 256, 0, stream>>>(gm, gl, glp);
    prep_sol_letters<<<(NROWS + 255) / 256, 256, 0, stream>>>(sols, sl, msk);
    init_state<<<(NROWS * KX + 255) / 256, 256, 0, stream>>>((unsigned short*)hX, scores, solvedf, lossacc);

    for (int t = 0; t < 6; ++t) {
        // h = X @ W0 + b0 + W0[286+t]  (turn one-hot folded into bias2)
        gemm_f16<true><<<dim3(MBLK, NP / 128), 256, 0, stream>>>(
            hX, KX, B0T, KX, hraw, NP, b0p, w0t + t * NP, KX / 32, pS, pS2);
        for (int l = 0; l < 4; ++l) {
            bn_apply_f<<<dim3(MBLK, NP / 128), 256, 0, stream>>>(
                hraw, pS, pS2, gammas + (size_t)l * H, betas + (size_t)l * H, hA);
            if (l < 3) {
                gemm_f16<true><<<dim3(MBLK, NP / 128), 256, 0, stream>>>(
                    hA, NP, WhT + (size_t)l * NP * NP, NP, hraw, NP, bhp + l * NP, nullptr,
                    NP / 32, pS, pS2);
            } else {
                gemm_f16<false><<<dim3(MBLK, OCP / 128), 256, 0, stream>>>(
                    hA, NP, BoT, NP, ybuf, OCP, boutp, nullptr, NP / 32, nullptr, nullptr);
            }
        }
        post_turn<<<NROWS / 4, 256, 0, stream>>>(ybuf, glp, gl, sl, msk, hX, scores, solvedf,
                                                 lossacc, gm, dout, t);
    }
    final_reduce<<<1, 256, 0, stream>>>(scores, solvedf, lossacc, dout);
}

// Round 9
// 1553.101 us; speedup vs baseline: 1.9003x; 1.0228x over previous
//
#include <hip/hip_runtime.h>

#define NROWS 8192
#define NG    12972
#define H     1000
#define NP    1024   // padded hidden width
#define KX    288    // padded hints width (multiple of 32)
#define OCP   256    // padded output cols
#define OC    130
#define EPSBN 1e-5f
#define MBLK  (NROWS / 128)   // 64 row-blocks => 64 stat partials

typedef __attribute__((ext_vector_type(8))) _Float16 f16x8;
typedef __attribute__((ext_vector_type(8))) unsigned short u16x8;
typedef __attribute__((ext_vector_type(4))) float f32x4;

__device__ __forceinline__ float lrelu(float x) { return x >= 0.f ? x : 0.2f * x; }

// ---------------- prep: transpose fp32 -> fp16, B^T layout ----------------
__global__ void transpose_f16(const float* __restrict__ src, int R, int C, int srcStride,
                              _Float16* __restrict__ dst, int Rp, int Cp) {
    __shared__ float tile[32][33];
    int k0 = blockIdx.x * 32;
    int n0 = blockIdx.y * 32;
    int tx = threadIdx.x, ty = threadIdx.y;  // 32 x 8
#pragma unroll
    for (int i = 0; i < 32; i += 8) {
        int k = k0 + ty + i, n = n0 + tx;
        tile[ty + i][tx] = (k < R && n < C) ? src[(size_t)k * srcStride + n] : 0.f;
    }
    __syncthreads();
#pragma unroll
    for (int i = 0; i < 32; i += 8) {
        int n = n0 + ty + i, k = k0 + tx;
        if (n < Cp && k < Rp) dst[(size_t)n * Rp + k] = (_Float16)tile[tx][ty + i];
    }
}

__global__ void prep_bias(const float* __restrict__ W0, const float* __restrict__ b0,
                          const float* __restrict__ bh, const float* __restrict__ bout,
                          float* __restrict__ b0p, float* __restrict__ w0t,
                          float* __restrict__ bhp, float* __restrict__ boutp) {
    int i = blockIdx.x * 256 + threadIdx.x;
    if (i < 1024) { b0p[i] = (i < H) ? b0[i] : 0.f; return; }
    i -= 1024;
    if (i < 6 * 1024) {
        int t = i >> 10, n = i & 1023;
        w0t[i] = (n < H) ? W0[(size_t)(286 + t) * H + n] : 0.f;
        return;
    }
    i -= 6 * 1024;
    if (i < 3 * 1024) {
        int l = i >> 10, n = i & 1023;
        bhp[i] = (n < H) ? bh[l * H + n] : 0.f;
        return;
    }
    i -= 3 * 1024;
    if (i < OCP) { boutp[i] = (i < OC) ? bout[i] : 0.f; }
}

// gl: letters (for hint update). glp: packed softmax offsets letter*5+p (5 bytes in uint2).
__global__ void prep_guess_letters(const float* __restrict__ gm, unsigned char* __restrict__ gl,
                                   uint2* __restrict__ glp) {
    int g = blockIdx.x * blockDim.x + threadIdx.x;
    if (g >= NG) return;
    unsigned off[5];
    for (int p = 0; p < 5; ++p) {
        int letter = 0;
        for (int c = 0; c < 26; ++c)
            if (gm[(size_t)g * 130 + c * 5 + p] > 0.5f) { letter = c; break; }
        gl[g * 8 + p] = (unsigned char)letter;
        off[p] = (unsigned)(letter * 5 + p);
    }
    gl[g * 8 + 5] = gl[g * 8 + 6] = gl[g * 8 + 7] = 0;
    glp[g] = make_uint2(off[0] | (off[1] << 8) | (off[2] << 16) | (off[3] << 24), off[4]);
}

__global__ void prep_sol_letters(const float* __restrict__ sols, unsigned char* __restrict__ sl,
                                 unsigned int* __restrict__ msk) {
    int r = blockIdx.x * blockDim.x + threadIdx.x;
    if (r >= NROWS) return;
    unsigned int m = 0;
    for (int p = 0; p < 5; ++p) {
        int letter = 0;
        for (int c = 0; c < 26; ++c)
            if (sols[(size_t)r * 130 + c * 5 + p] > 0.5f) { letter = c; break; }
        sl[r * 8 + p] = (unsigned char)letter;
        m |= 1u << letter;
    }
    sl[r * 8 + 5] = sl[r * 8 + 6] = sl[r * 8 + 7] = 0;
    msk[r] = m;
}

__global__ void init_state(unsigned short* __restrict__ hX, float* __restrict__ scores,
                           int* __restrict__ solvedf, float* __restrict__ lossacc) {
    int i = blockIdx.x * blockDim.x + threadIdx.x;
    if (i < NROWS * KX) hX[i] = 0;
    if (i < NROWS) { scores[i] = 7.f; solvedf[i] = 0; }
    if (i == 0) lossacc[0] = 0.f;
}

// ---------------- GEMM fp16: C = A*B^T + bias, fused column stats ----------------
// m97 structure: 128x128 tile, 4 waves (2x2), templated BK (32 or 64), single LDS buffer,
// global_load_lds width-16 staging. BK=64: 32 MFMA : 16 ds_read per step, half the barriers.
// K-chunk accumulation order identical for both BK -> bit-identical results.
template <int BK, bool HALF_C>
__global__ __launch_bounds__(256, 2) void gemm_f16(
    const _Float16* __restrict__ A, int lda,
    const _Float16* __restrict__ B, int ldb,
    void* __restrict__ Cv, int ldc,
    const float* __restrict__ bias1, const float* __restrict__ bias2, int kiter,
    float* __restrict__ pS, float* __restrict__ pS2) {
    constexpr int NCH = BK / 8;           // 16B staging chunks per thread per K-step
    constexpr int ABYTES = 256 * BK;      // A region bytes (128 rows x BK halves)
    constexpr int KSUB = BK / 32;         // MFMA sub-steps per K-step
    constexpr int AW = 16 * BK;           // A 16B-words per K-step
    __shared__ char smem[512 * BK];
    const int tid = threadIdx.x;
    const int lane = tid & 63;
    const int rowBase = blockIdx.x * 128;
    const int colBase = blockIdx.y * 128;
    const int wm = (tid >> 6) & 1;
    const int wn = tid >> 7;

    const _Float16* gsrc[NCH];
    int ldsuni[NCH];
#pragma unroll
    for (int i = 0; i < NCH; ++i) {
        int w = i * 256 + tid;
        const _Float16* plane;
        int off;
        if (w < AW) {
            int r = w & 127, kb = w >> 7;
            plane = A;
            off = (rowBase + r) * lda + kb * 8;
        } else {
            int v = w - AW;
            int col = v & 127, kb = v >> 7;
            plane = B;
            off = (colBase + col) * ldb + kb * 8;
        }
        gsrc[i] = plane + off;
        ldsuni[i] = (i * 256 + (tid & ~63)) * 16;  // wave-uniform byte base
    }

    f32x4 acc[4][4];
    const f32x4 z = {0.f, 0.f, 0.f, 0.f};
#pragma unroll
    for (int m = 0; m < 4; ++m)
#pragma unroll
        for (int n = 0; n < 4; ++n) acc[m][n] = z;

    const int aro = (lane >> 4) * 2048 + (wm * 64 + (lane & 15)) * 16;
    const int bco = ABYTES + (lane >> 4) * 2048 + (wn * 64 + (lane & 15)) * 16;

    for (int t = 0; t < kiter; ++t) {
#pragma unroll
        for (int i = 0; i < NCH; ++i)
            __builtin_amdgcn_global_load_lds(
                (const __attribute__((address_space(1))) void*)(gsrc[i] + (size_t)t * BK),
                (__attribute__((address_space(3))) void*)(smem + ldsuni[i]), 16, 0, 0);
        __syncthreads();

        f16x8 a_f[KSUB][4], b_f[KSUB][4];
#pragma unroll
        for (int ks = 0; ks < KSUB; ++ks) {
#pragma unroll
            for (int m = 0; m < 4; ++m) a_f[ks][m] = *(const f16x8*)(smem + ks * 8192 + aro + m * 256);
#pragma unroll
            for (int n = 0; n < 4; ++n) b_f[ks][n] = *(const f16x8*)(smem + ks * 8192 + bco + n * 256);
        }
#pragma unroll
        for (int ks = 0; ks < KSUB; ++ks)
#pragma unroll
            for (int m = 0; m < 4; ++m)
#pragma unroll
                for (int n = 0; n < 4; ++n)
                    acc[m][n] = __builtin_amdgcn_mfma_f32_16x16x32_f16(a_f[ks][m], b_f[ks][n],
                                                                       acc[m][n], 0, 0, 0);
        __syncthreads();
    }

    // epilogue (smem contents dead; last loop iter ended with __syncthreads)
    float* sS  = (float*)smem;           // [2][128]
    float* sS2 = (float*)smem + 256;     // [2][128]
    const int lane16 = lane & 15, lanehi = lane >> 4;
#pragma unroll
    for (int n = 0; n < 4; ++n) {
        int col = colBase + wn * 64 + n * 16 + lane16;
        float bv = bias1[col] + (bias2 ? bias2[col] : 0.f);
        float s = 0.f, s2 = 0.f;
#pragma unroll
        for (int m = 0; m < 4; ++m) {
            int row0 = rowBase + wm * 64 + m * 16 + lanehi * 4;
#pragma unroll
            for (int r = 0; r < 4; ++r) {
                float cv = acc[m][n][r] + bv;
                if constexpr (HALF_C)
                    ((_Float16*)Cv)[(size_t)(row0 + r) * ldc + col] = (_Float16)cv;
                else
                    ((float*)Cv)[(size_t)(row0 + r) * ldc + col] = cv;
                s += cv; s2 += cv * cv;
            }
        }
        if (pS) {
            s += __shfl_xor(s, 16);  s += __shfl_xor(s, 32);
            s2 += __shfl_xor(s2, 16); s2 += __shfl_xor(s2, 32);
            if (lanehi == 0) {
                int lcol = wn * 64 + n * 16 + lane16;
                sS[wm * 128 + lcol] = s;
                sS2[wm * 128 + lcol] = s2;
            }
        }
    }
    if (pS) {
        __syncthreads();
        if (tid < 128) {
            int col = colBase + tid;
            pS[(size_t)blockIdx.x * NP + col] = sS[tid] + sS[128 + tid];
            pS2[(size_t)blockIdx.x * NP + col] = sS2[tid] + sS2[128 + tid];
        }
    }
}

// ---------------- fused BN finalize + apply + lrelu (fp16 in, fp16 out) ----------------
__global__ __launch_bounds__(256) void bn_apply_f(
    const _Float16* __restrict__ hraw, const float* __restrict__ pS, const float* __restrict__ pS2,
    const float* __restrict__ gamma, const float* __restrict__ beta,
    _Float16* __restrict__ oh) {
    __shared__ float la[128], lb[128];
    const int tid = threadIdx.x;
    const int rowBase = blockIdx.x * 128;
    const int colBase = blockIdx.y * 128;
    if (tid < 128) {
        int col = colBase + tid;
        float s = 0.f;
        for (int j = 0; j < MBLK; ++j) s += pS[(size_t)j * NP + col];
        la[tid] = s;
    } else {
        int col = colBase + tid - 128;
        float s2 = 0.f;
        for (int j = 0; j < MBLK; ++j) s2 += pS2[(size_t)j * NP + col];
        lb[tid - 128] = s2;
    }
    __syncthreads();
    if (tid < 128) {
        int col = colBase + tid;
        float a = 0.f, b = 0.f;
        if (col < H) {
            float mean = la[tid] * (1.f / NROWS);
            float var = lb[tid] * (1.f / NROWS) - mean * mean;
            float inv = rsqrtf(var + EPSBN);
            a = gamma[col] * inv;
            b = beta[col] - mean * a;
        }
        la[tid] = a;
        lb[tid] = b;
    }
    __syncthreads();
    const int c8 = (tid & 15) * 8;
    float ar[8], br[8];
#pragma unroll
    for (int j = 0; j < 8; ++j) { ar[j] = la[c8 + j]; br[j] = lb[c8 + j]; }
#pragma unroll
    for (int i = 0; i < 8; ++i) {
        int row = i * 16 + (tid >> 4);
        const u16x8 v = *(const u16x8*)(hraw + (size_t)(rowBase + row) * NP + colBase + c8);
        u16x8 o;
#pragma unroll
        for (int j = 0; j < 8; ++j) {
            float x = (float)__builtin_bit_cast(_Float16, (unsigned short)v[j]);
            o[j] = __builtin_bit_cast(unsigned short, (_Float16)lrelu(ar[j] * x + br[j]));
        }
        *(u16x8*)((unsigned short*)oh + (size_t)(rowBase + row) * NP + colBase + c8) = o;
    }
}

// ---------------- fused per-turn tail: softmax + loss + vocab argmax + hints ----------------
// 8 rows/block: per-word overhead (glp load, offset extract, loop) amortized over 8 rows,
// glp L2 traffic halved vs 4 rows/block. SoA pk[8][132] keeps gathers conflict-light.
__global__ __launch_bounds__(256) void post_turn(
    const float* __restrict__ ybuf, const uint2* __restrict__ glp,
    const unsigned char* __restrict__ gl, const unsigned char* __restrict__ sl,
    const unsigned int* __restrict__ msk, _Float16* __restrict__ hX,
    float* __restrict__ scores, int* __restrict__ solvedf, float* __restrict__ lossacc,
    const float* __restrict__ gm, float* __restrict__ dout, int turn) {
    const int r0 = blockIdx.x * 8;
    __shared__ float pk[8][132];         // SoA: pk[row][letterOffset]
    __shared__ float lcon[40];
    __shared__ float wb[4][8];
    __shared__ int wi[4][8];
    __shared__ int fidx[8];
    const int tid = threadIdx.x;

    if (tid < 40) {
        int row = tid / 5, p = tid - row * 5;
        const float* yr = ybuf + (size_t)(r0 + row) * OCP + p;
        float m = -1e30f;
#pragma unroll
        for (int c = 0; c < 26; ++c) m = fmaxf(m, yr[c * 5]);
        float e[26];
        float s = 0.f;
#pragma unroll
        for (int c = 0; c < 26; ++c) { e[c] = expf(yr[c * 5] - m); s += e[c]; }
        float inv = 1.f / s;
#pragma unroll
        for (int c = 0; c < 26; ++c) pk[row][c * 5 + p] = e[c] * inv;
        lcon[tid] = logf(s) + m - yr[sl[(size_t)(r0 + row) * 8 + p] * 5];
    }
    __syncthreads();

    // vocab scan: 8 rows per thread, words strided over 256 threads
    float bb[8];
    int ii[8];
#pragma unroll
    for (int r = 0; r < 8; ++r) { bb[r] = -1e30f; ii[r] = 1 << 30; }
    for (int g = tid; g < NG; g += 256) {
        uint2 w = glp[g];
        int o0 = w.x & 255, o1 = (w.x >> 8) & 255, o2 = (w.x >> 16) & 255,
            o3 = w.x >> 24, o4 = w.y & 255;
#pragma unroll
        for (int r = 0; r < 8; ++r) {
            // same left-assoc add order as reference gather
            float v = pk[r][o0] + pk[r][o1]; v += pk[r][o2]; v += pk[r][o3]; v += pk[r][o4];
            if (v > bb[r]) { bb[r] = v; ii[r] = g; }
        }
    }
#pragma unroll
    for (int off = 1; off < 64; off <<= 1) {
#pragma unroll
        for (int r = 0; r < 8; ++r) {
            float o = __shfl_xor(bb[r], off);
            int oi = __shfl_xor(ii[r], off);
            if (o > bb[r] || (o == bb[r] && oi < ii[r])) { bb[r] = o; ii[r] = oi; }
        }
    }
    const int wid = tid >> 6, lane = tid & 63;
    if (lane == 0) {
#pragma unroll
        for (int r = 0; r < 8; ++r) { wb[wid][r] = bb[r]; wi[wid][r] = ii[r]; }
    }
    __syncthreads();

    if (tid < 8) {
        float b = wb[0][tid]; int x = wi[0][tid];
#pragma unroll
        for (int wv = 1; wv < 4; ++wv)
            if (wb[wv][tid] > b || (wb[wv][tid] == b && wi[wv][tid] < x)) { b = wb[wv][tid]; x = wi[wv][tid]; }
        fidx[tid] = x;
        // hints / scores / solved for row r0+tid
        int r = r0 + tid;
        const unsigned char* q = gl + x * 8;
        const unsigned char* so = sl + (size_t)r * 8;
        unsigned int mk = msk[r];
        _Float16* hrow = hX + (size_t)r * KX;
        int allg = 1;
#pragma unroll
        for (int p = 0; p < 5; ++p) {
            int g = q[p];
            int off;
            if (g == so[p]) {
                off = g * 5 + p;  // green
            } else {
                allg = 0;
                off = ((mk >> g) & 1u) ? (130 + g * 5 + p) : (260 + g);  // yellow : black
            }
            hrow[off] = (_Float16)((float)hrow[off] + 1.f);
        }
        solvedf[r] = allg;
        if (allg && scores[r] > (float)(turn + 1)) scores[r] = (float)(turn + 1);
    }
    if (tid == 16 && turn >= 1) {
        float t = 0.f;
#pragma unroll
        for (int j = 0; j < 40; ++j) t += lcon[j];
        atomicAdd(lossacc, t * (1.f / (NROWS * 5)));
    }
    __syncthreads();
    if (turn == 0 && blockIdx.x == 0 && tid >= 64 && tid < 64 + OC) {
        dout[3 + tid - 64] = gm[(size_t)fidx[0] * OC + (tid - 64)];
    }
}

__global__ void final_reduce(const float* __restrict__ scores, const int* __restrict__ solvedf,
                             const float* __restrict__ lossacc, float* __restrict__ dout) {
    __shared__ float rs[256];
    __shared__ int ri[256];
    int tid = threadIdx.x;
    float s = 0.f;
    int c = 0;
    for (int r = tid; r < NROWS; r += 256) { s += scores[r]; c += solvedf[r]; }
    rs[tid] = s; ri[tid] = c;
    __syncthreads();
    for (int off = 128; off > 0; off >>= 1) {
        if (tid < off) { rs[tid] += rs[tid + off]; ri[tid] += ri[tid + off]; }
        __syncthreads();
    }
    if (tid == 0) {
        dout[0] = lossacc[0];
        dout[1] = rs[0];
        dout[2] = (float)ri[0];
    }
}

// ---------------- launch ----------------
extern "C" void kernel_launch(void* const* d_in, const int* in_sizes, int n_in,
                              void* d_out, int out_size, void* d_ws, size_t ws_size,
                              hipStream_t stream) {
    const float* sols   = (const float*)d_in[0];
    const float* gm     = (const float*)d_in[1];
    const float* W0     = (const float*)d_in[2];
    const float* b0     = (const float*)d_in[3];
    const float* gammas = (const float*)d_in[4];
    const float* betas  = (const float*)d_in[5];
    const float* Wh     = (const float*)d_in[6];
    const float* bh     = (const float*)d_in[7];
    const float* Wout   = (const float*)d_in[8];
    const float* bout   = (const float*)d_in[9];
    float* dout = (float*)d_out;

    char* p = (char*)d_ws;
    auto alloc = [&](size_t bytes) { void* r = (void*)p; p += (bytes + 255) & ~(size_t)255; return r; };
    _Float16* hX   = (_Float16*)alloc((size_t)NROWS * KX * 2);
    _Float16* hA   = (_Float16*)alloc((size_t)NROWS * NP * 2);
    _Float16* hraw = (_Float16*)alloc((size_t)NROWS * NP * 2);
    float* ybuf    = (float*)alloc((size_t)NROWS * OCP * 4);
    _Float16* B0T = (_Float16*)alloc((size_t)NP * KX * 2);
    _Float16* WhT = (_Float16*)alloc((size_t)3 * NP * NP * 2);
    _Float16* BoT = (_Float16*)alloc((size_t)OCP * NP * 2);
    float* b0p   = (float*)alloc(NP * 4);
    float* w0t   = (float*)alloc(6 * NP * 4);
    float* bhp   = (float*)alloc(3 * NP * 4);
    float* boutp = (float*)alloc(OCP * 4);
    float* pS    = (float*)alloc((size_t)MBLK * NP * 4);
    float* pS2   = (float*)alloc((size_t)MBLK * NP * 4);
    float* scores  = (float*)alloc(NROWS * 4);
    float* lossacc = (float*)alloc(256);
    int* solvedf = (int*)alloc(NROWS * 4);
    unsigned char* gl = (unsigned char*)alloc(NG * 8);
    uint2* glp = (uint2*)alloc(NG * 8);
    unsigned char* sl = (unsigned char*)alloc(NROWS * 8);
    unsigned int* msk = (unsigned int*)alloc(NROWS * 4);

    // ---- prep ----
    transpose_f16<<<dim3(KX / 32, NP / 32), dim3(32, 8), 0, stream>>>(W0, 286, H, H, B0T, KX, NP);
    for (int l = 0; l < 3; ++l)
        transpose_f16<<<dim3(NP / 32, NP / 32), dim3(32, 8), 0, stream>>>(
            Wh + (size_t)l * H * H, H, H, H, WhT + (size_t)l * NP * NP, NP, NP);
    transpose_f16<<<dim3(NP / 32, OCP / 32), dim3(32, 8), 0, stream>>>(Wout, H, OC, OC, BoT, NP, OCP);
    prep_bias<<<41, 256, 0, stream>>>(W0, b0, bh, bout, b0p, w0t, bhp, boutp);
    prep_guess_letters<<<(NG + 255) / 256, 256, 0, stream>>>(gm, gl, glp);
    prep_sol_letters<<<(NROWS + 255) / 256, 256, 0, stream>>>(sols, sl, msk);
    init_state<<<(NROWS * KX + 255) / 256, 256, 0, stream>>>((unsigned short*)hX, scores, solvedf, lossacc);

    for (int t = 0; t < 6; ++t) {
        // h = X @ W0 + b0 + W0[286+t]  (turn one-hot folded into bias2)
        gemm_f16<32, true><<<dim3(MBLK, NP / 128), 256, 0, stream>>>(
            hX, KX, B0T, KX, hraw, NP, b0p, w0t + t * NP, KX / 32, pS, pS2);
        for (int l = 0; l < 4; ++l) {
            bn_apply_f<<<dim3(MBLK, NP / 128), 256, 0, stream>>>(
                hraw, pS, pS2, gammas + (size_t)l * H, betas + (size_t)l * H, hA);
            if (l < 3) {
                gemm_f16<64, true><<<dim3(MBLK, NP / 128), 256, 0, stream>>>(
                    hA, NP, WhT + (size_t)l * NP * NP, NP, hraw, NP, bhp + l * NP, nullptr,
                    NP / 64, pS, pS2);
            } else {
                gemm_f16<64, false><<<dim3(MBLK, OCP / 128), 256, 0, stream>>>(
                    hA, NP, BoT, NP, ybuf, OCP, boutp, nullptr, NP / 64, nullptr, nullptr);
            }
        }
        post_turn<<<NROWS / 8, 256, 0, stream>>>(ybuf, glp, gl, sl, msk, hX, scores, solvedf,
                                                 lossacc, gm, dout, t);
    }
    final_reduce<<<1, 256, 0, stream>>>(scores, solvedf, lossacc, dout);
}